// Round 12
// baseline (4805.195 us; speedup 1.0000x reference)
//
#include <hip/hip_runtime.h>
#include <hip/hip_bf16.h>

#define D 128
#define CH 2048          // edges per k_binA block
#define BSH 7            // log2(nodes per bucket) -> 128
#define BN (1 << BSH)
#define NBMAX 1024       // max buckets supported (n <= 131072)
#define MAXBE 2048       // max edges per bucket held in LDS (mean 1024, sigma 32)
#define CNT_BLK 256      // blocks doing bucket counting in k_prep

typedef __attribute__((ext_vector_type(8))) short short8;
typedef __attribute__((ext_vector_type(4))) float f32x4;
typedef __attribute__((ext_vector_type(4))) int int4v;
typedef __attribute__((ext_vector_type(2))) int int2v;
typedef __attribute__((ext_vector_type(4))) float float4v;
typedef __attribute__((ext_vector_type(4))) unsigned uint4v;
typedef __attribute__((ext_vector_type(2))) unsigned uint2v;
typedef _Float16 half2_t __attribute__((ext_vector_type(2)));

__device__ __forceinline__ unsigned short us_bf16(float f) {
    return __bfloat16_as_ushort(__float2bfloat16(f));
}
__device__ __forceinline__ unsigned pack_bf16(float a, float b) {
    return (unsigned)us_bf16(a) | ((unsigned)us_bf16(b) << 16);
}
__device__ __forceinline__ unsigned pack_f16(float a, float b) {
    unsigned short ua = __builtin_bit_cast(unsigned short, (_Float16)a);
    unsigned short ub = __builtin_bit_cast(unsigned short, (_Float16)b);
    return (unsigned)ua | ((unsigned)ub << 16);
}
__device__ __forceinline__ unsigned dup_f16(float a) {
    unsigned short ua = __builtin_bit_cast(unsigned short, (_Float16)a);
    return (unsigned)ua | ((unsigned)ua << 16);
}
__device__ __forceinline__ float f16_lo(int y) {
    return (float)__builtin_bit_cast(_Float16, (unsigned short)(y & 0xffff));
}
__device__ __forceinline__ half2_t as_h2(unsigned u) {
    return __builtin_bit_cast(half2_t, u);
}
__device__ __forceinline__ half2_t shfl_h2(half2_t v, int mask) {
    return __builtin_bit_cast(half2_t,
        (unsigned)__shfl_xor(__builtin_bit_cast(int, v), mask));
}

// ---------- prep: x->f16, W->bf16 transposed, per-bucket LDS count ----------
__global__ __launch_bounds__(256) void k_prep(const float* __restrict__ x,
                                              unsigned* __restrict__ xh, int nf4,
                                              const float* __restrict__ W1,
                                              const float* __restrict__ W2,
                                              unsigned short* __restrict__ W1t,
                                              unsigned short* __restrict__ W2t,
                                              const int* __restrict__ tgt,
                                              int* __restrict__ bcnt, int E, int nbuk) {
    int tid = threadIdx.x;
    int i0 = blockIdx.x * blockDim.x + tid;
    int stride = gridDim.x * blockDim.x;
    const float4v* x4 = reinterpret_cast<const float4v*>(x);
    uint2v* xh2 = reinterpret_cast<uint2v*>(xh);
    for (int i = i0; i < nf4; i += stride) {
        float4v v = x4[i];
        uint2v o;
        o.x = pack_f16(v.x, v.y);
        o.y = pack_f16(v.z, v.w);
        xh2[i] = o;
    }
    if (i0 < 16384) {
        int k = i0 >> 7, nn = i0 & 127;
        W1t[nn * 128 + k] = us_bf16(W1[i0]);
        W2t[nn * 128 + k] = us_bf16(W2[i0]);
    }
    __shared__ int hist[NBMAX];
    if (blockIdx.x < CNT_BLK) {
        for (int j = tid; j < NBMAX; j += 256) hist[j] = 0;
        __syncthreads();
        int c0 = blockIdx.x * 256 + tid;
        int cstride = CNT_BLK * 256;
        int E4 = E >> 2;
        const int4v* tgt4 = reinterpret_cast<const int4v*>(tgt);
        for (int q = c0; q < E4; q += cstride) {
            int4v t4 = __builtin_nontemporal_load(&tgt4[q]);
            atomicAdd(&hist[t4.x >> BSH], 1);
            atomicAdd(&hist[t4.y >> BSH], 1);
            atomicAdd(&hist[t4.z >> BSH], 1);
            atomicAdd(&hist[t4.w >> BSH], 1);
        }
        for (int e = E4 * 4 + c0; e < E; e += cstride)
            atomicAdd(&hist[tgt[e] >> BSH], 1);
        __syncthreads();
        for (int j = tid; j < nbuk; j += 256)
            if (hist[j] > 0) atomicAdd(&bcnt[j], hist[j]);
    }
}

// ---------- tiny: scan bucket counts -> bbase/bcur ----------
__global__ __launch_bounds__(256) void k_scanB(const int* __restrict__ bcnt,
                                               int* __restrict__ bbase,
                                               int* __restrict__ bcur,
                                               int nbuk, int E) {
    __shared__ int sc[256];
    int t = threadIdx.x;
    int v[4]; int tsum = 0;
    #pragma unroll
    for (int k = 0; k < 4; ++k) {
        int idx = 4 * t + k;
        v[k] = (idx < nbuk) ? bcnt[idx] : 0;
        tsum += v[k];
    }
    sc[t] = tsum; __syncthreads();
    for (int off = 1; off < 256; off <<= 1) {
        int o = (t >= off) ? sc[t - off] : 0;
        __syncthreads();
        sc[t] += o;
        __syncthreads();
    }
    int excl = sc[t] - tsum;
    #pragma unroll
    for (int k = 0; k < 4; ++k) {
        int idx = 4 * t + k;
        if (idx < nbuk) { bbase[idx] = excl; bcur[idx] = excl; }
        excl += v[k];
    }
    if (t == 0) bbase[nbuk] = E;
}

// ---------- pass A: LDS-binned bucket append ----------
__global__ __launch_bounds__(256) void k_binA(
    const int* __restrict__ src, const int* __restrict__ tgt,
    const float* __restrict__ ew, int* __restrict__ bcur,
    int2* __restrict__ stage, int E, int nbuk)
{
    __shared__ int2 recs[CH];
    __shared__ unsigned short bslot[CH];
    __shared__ int sh[NBMAX];
    __shared__ int lbase[NBMAX];
    __shared__ int gofs[NBMAX];
    __shared__ int sc[256];

    int tid = threadIdx.x;
    int c0 = blockIdx.x * CH;
    int chunkCnt = min(CH, E - c0);

    for (int j = tid; j < NBMAX; j += 256) sh[j] = 0;
    __syncthreads();

    int myb[8], mypos[8], mysrc[8]; unsigned myy[8];
    #pragma unroll
    for (int k = 0; k < 8; ++k) {
        int idx = k * 256 + tid;
        myb[k] = -1;
        if (idx < chunkCnt) {
            int e = c0 + idx;
            int t = __builtin_nontemporal_load(&tgt[e]);
            int b = t >> BSH;
            float expw = __expf(__builtin_nontemporal_load(&ew[e]));
            unsigned short h = __builtin_bit_cast(unsigned short, (_Float16)expw);
            myb[k] = b;
            myy[k] = ((unsigned)(t & (BN - 1)) << 16) | (unsigned)h;
            mysrc[k] = __builtin_nontemporal_load(&src[e]);
            mypos[k] = atomicAdd(&sh[b], 1);
        }
    }
    __syncthreads();
    // scan NBMAX bins, 4 per thread
    int v[4]; int tsum = 0;
    #pragma unroll
    for (int k = 0; k < 4; ++k) { v[k] = sh[4 * tid + k]; tsum += v[k]; }
    sc[tid] = tsum;
    __syncthreads();
    for (int off = 1; off < 256; off <<= 1) {
        int o = (tid >= off) ? sc[tid - off] : 0;
        __syncthreads();
        sc[tid] += o;
        __syncthreads();
    }
    int excl = sc[tid] - tsum;
    #pragma unroll
    for (int k = 0; k < 4; ++k) {
        int idx = 4 * tid + k;
        lbase[idx] = excl;
        if (idx < nbuk && v[k] > 0) {
            int gb = atomicAdd(&bcur[idx], v[k]);
            gofs[idx] = gb - excl;
        }
        excl += v[k];
    }
    __syncthreads();
    #pragma unroll
    for (int k = 0; k < 8; ++k) {
        if (myb[k] >= 0) {
            int slot = lbase[myb[k]] + mypos[k];
            recs[slot] = make_int2(mysrc[k], (int)myy[k]);
            bslot[slot] = (unsigned short)myb[k];
        }
    }
    __syncthreads();
    for (int i = tid; i < chunkCnt; i += 256) {
        int b = bslot[i];
        stage[gofs[b] + i] = recs[i];
    }
}

// ---------- fused: per-bucket CSR-in-LDS + softmax normalize + gather + sphere-norm ----------
__global__ __launch_bounds__(256) void k_fuse(
    const int* __restrict__ bbase, const int2* __restrict__ stage,
    const uint4v* __restrict__ xh4, uint4v* __restrict__ cmb4, int n)
{
    __shared__ int2 lcsr[MAXBE];       // 16 KB
    __shared__ float ldenom[BN];
    __shared__ int lbase[BN];
    __shared__ int lcur[BN];
    __shared__ int sc[256];

    int b = blockIdx.x;
    int tid = threadIdx.x;
    int node0 = b << BSH;
    int nn = min(BN, n - node0);
    int s0 = bbase[b], s1 = bbase[b + 1];
    int cnt = s1 - s0;

    if (tid < BN) { ldenom[tid] = 0.f; lcur[tid] = 0; }
    __syncthreads();

    const int2v* stage2 = reinterpret_cast<const int2v*>(stage);

    // pass 1: per-node count + softmax denominator
    for (int i = s0 + tid; i < s1; i += 256) {
        int2v rec = stage2[i];
        int tl = ((unsigned)rec.y) >> 16;
        atomicAdd(&lcur[tl], 1);
        atomicAdd(&ldenom[tl], f16_lo(rec.y));
    }
    __syncthreads();

    int v = (tid < BN) ? lcur[tid] : 0;
    sc[tid] = v;
    if (tid < BN) {
        float d = ldenom[tid];
        ldenom[tid] = (d > 0.f) ? (1.f / d) : 0.f;
    }
    __syncthreads();
    for (int off = 1; off < 256; off <<= 1) {
        int o = (tid >= off) ? sc[tid - off] : 0;
        __syncthreads();
        sc[tid] += o;
        __syncthreads();
    }
    int excl = sc[tid] - v;
    if (tid < BN) lbase[tid] = excl;
    __syncthreads();
    if (tid < BN) lcur[tid] = excl;
    __syncthreads();

    bool fits = (cnt <= MAXBE);
    if (fits) {
        // pass 2: scatter normalized records into LDS csr
        for (int i = s0 + tid; i < s1; i += 256) {
            int2v rec = stage2[i];
            int tl = ((unsigned)rec.y) >> 16;
            float wn = f16_lo(rec.y) * ldenom[tl];
            int pos = atomicAdd(&lcur[tl], 1);
            lcsr[pos] = make_int2(rec.x, (int)dup_f16(wn));
        }
    }
    __syncthreads();

    // gather: wave wv handles nodes wv, wv+4, ...
    int wv = tid >> 6, lane = tid & 63;
    int eg = lane >> 4, dg = lane & 15;
    for (int j = wv; j < nn; j += 4) {
        half2_t h0 = (half2_t)0, h1 = (half2_t)0, h2 = (half2_t)0, h3 = (half2_t)0;
        if (fits) {
            int r0 = lbase[j];
            int cj = lcur[j] - r0;
            int lastj = (cj > 0) ? cj - 1 : 0;
            for (int basee = 0; basee < cj; basee += 4) {
                int e = basee + eg;
                bool valid = e < cj;
                int2 cr = lcsr[r0 + (valid ? e : lastj)];
                half2_t w2 = as_h2(valid ? (unsigned)cr.y : 0u);
                uint4v vr = xh4[cr.x * 16 + dg];
                h0 += w2 * as_h2(vr.x);
                h1 += w2 * as_h2(vr.y);
                h2 += w2 * as_h2(vr.z);
                h3 += w2 * as_h2(vr.w);
            }
        } else {
            // slow fallback (statistically unreachable): filter-scan whole segment
            float invd = ldenom[j];
            for (int i = 0; i < cnt; i += 4) {
                int e = i + eg;
                bool valid = e < cnt;
                int2v rec = stage2[s0 + (valid ? e : cnt - 1)];
                int tl = ((unsigned)rec.y) >> 16;
                bool mine = valid && (tl == j);
                float wn = mine ? f16_lo(rec.y) * invd : 0.f;
                half2_t w2 = as_h2(dup_f16(wn));
                uint4v vr = xh4[(mine ? rec.x : 0) * 16 + dg];
                h0 += w2 * as_h2(vr.x);
                h1 += w2 * as_h2(vr.y);
                h2 += w2 * as_h2(vr.z);
                h3 += w2 * as_h2(vr.w);
            }
        }

        // reduce across the 4 edge-groups
        h0 += shfl_h2(h0, 16); h0 += shfl_h2(h0, 32);
        h1 += shfl_h2(h1, 16); h1 += shfl_h2(h1, 32);
        h2 += shfl_h2(h2, 16); h2 += shfl_h2(h2, 32);
        h3 += shfl_h2(h3, 16); h3 += shfl_h2(h3, 32);

        float a0 = (float)h0.x, a1 = (float)h0.y, a2 = (float)h1.x, a3 = (float)h1.y;
        float a4 = (float)h2.x, a5 = (float)h2.y, a6 = (float)h3.x, a7 = (float)h3.y;

        float ss = a0 * a0;
        ss = fmaf(a1, a1, ss); ss = fmaf(a2, a2, ss); ss = fmaf(a3, a3, ss);
        ss = fmaf(a4, a4, ss); ss = fmaf(a5, a5, ss); ss = fmaf(a6, a6, ss);
        ss = fmaf(a7, a7, ss);
        #pragma unroll
        for (int off = 8; off; off >>= 1) ss += __shfl_xor(ss, off);
        float rn = 1.f / (sqrtf(ss) + 1e-9f);

        if (eg == 0) {
            int node = node0 + j;
            uint4v hx = xh4[node * 16 + dg];
            half2_t x0 = as_h2(hx.x), x1 = as_h2(hx.y), x2 = as_h2(hx.z), x3 = as_h2(hx.w);
            uint4v o;
            o.x = pack_bf16((float)x0.x + a0 * rn, (float)x0.y + a1 * rn);
            o.y = pack_bf16((float)x1.x + a2 * rn, (float)x1.y + a3 * rn);
            o.z = pack_bf16((float)x2.x + a4 * rn, (float)x2.y + a5 * rn);
            o.w = pack_bf16((float)x3.x + a6 * rn, (float)x3.y + a7 * rn);
            cmb4[node * 16 + dg] = o;
        }
    }
}

// ---------- MLP + LN via MFMA: 64 nodes/block; W read from global (L1/L2) ----------
__global__ __launch_bounds__(256) void k_mlp(
    const uint4v* __restrict__ cmb4,
    const unsigned short* __restrict__ W1t, const unsigned short* __restrict__ W2t,
    const float* __restrict__ b1, const float* __restrict__ b2,
    const float* __restrict__ gamma, const float* __restrict__ beta,
    float* __restrict__ out, int n)
{
    __shared__ __align__(16) unsigned short sA[64][136];

    int node0 = blockIdx.x * 64;
    int w = threadIdx.x >> 6;
    int lane = threadIdx.x & 63;
    int lr = lane & 15;
    int lg = lane >> 4;
    int mr = w * 16;

    for (int idx = threadIdx.x; idx < 64 * 16; idx += 256) {
        int row = idx >> 4, seg = idx & 15;
        int gr = node0 + row; if (gr >= n) gr = n - 1;
        uint4v v = cmb4[gr * 16 + seg];
        *reinterpret_cast<uint4v*>(&sA[row][seg * 8]) = v;
    }
    __syncthreads();

    short8 aF[4];
    #pragma unroll
    for (int kt = 0; kt < 4; ++kt)
        aF[kt] = *reinterpret_cast<const short8*>(&sA[mr + lr][kt * 32 + lg * 8]);

    #pragma unroll
    for (int nt = 0; nt < 8; ++nt) {
        f32x4 c = {0.f, 0.f, 0.f, 0.f};
        #pragma unroll
        for (int kt = 0; kt < 4; ++kt) {
            short8 bF = *reinterpret_cast<const short8*>(
                &W1t[(nt * 16 + lr) * 128 + kt * 32 + lg * 8]);
            c = __builtin_amdgcn_mfma_f32_16x16x32_bf16(aF[kt], bF, c, 0, 0, 0);
        }
        float b1v = b1[nt * 16 + lr];
        #pragma unroll
        for (int reg = 0; reg < 4; ++reg) {
            float h = fmaxf(c[reg] + b1v, 0.f);
            sA[mr + lg * 4 + reg][nt * 16 + lr] = us_bf16(h);
        }
    }
    __syncthreads();

    short8 a2F[4];
    #pragma unroll
    for (int kt = 0; kt < 4; ++kt)
        a2F[kt] = *reinterpret_cast<const short8*>(&sA[mr + lr][kt * 32 + lg * 8]);

    f32x4 c2[8];
    float b2v[8], gv[8], bev[8];
    #pragma unroll
    for (int nt = 0; nt < 8; ++nt) {
        c2[nt] = (f32x4){0.f, 0.f, 0.f, 0.f};
        #pragma unroll
        for (int kt = 0; kt < 4; ++kt) {
            short8 bF = *reinterpret_cast<const short8*>(
                &W2t[(nt * 16 + lr) * 128 + kt * 32 + lg * 8]);
            c2[nt] = __builtin_amdgcn_mfma_f32_16x16x32_bf16(a2F[kt], bF, c2[nt], 0, 0, 0);
        }
        int col = nt * 16 + lr;
        b2v[nt] = b2[col]; gv[nt] = gamma[col]; bev[nt] = beta[col];
    }

    float rs[4] = {0.f, 0.f, 0.f, 0.f}, sq[4] = {0.f, 0.f, 0.f, 0.f};
    #pragma unroll
    for (int nt = 0; nt < 8; ++nt)
        #pragma unroll
        for (int reg = 0; reg < 4; ++reg) {
            float v = c2[nt][reg] + b2v[nt];
            rs[reg] += v; sq[reg] += v * v;
        }
    #pragma unroll
    for (int off = 1; off <= 8; off <<= 1)
        #pragma unroll
        for (int reg = 0; reg < 4; ++reg) {
            rs[reg] += __shfl_xor(rs[reg], off);
            sq[reg] += __shfl_xor(sq[reg], off);
        }
    float mu[4], rstd[4];
    #pragma unroll
    for (int reg = 0; reg < 4; ++reg) {
        mu[reg] = rs[reg] * (1.f / 128.f);
        float var = sq[reg] * (1.f / 128.f) - mu[reg] * mu[reg];
        rstd[reg] = rsqrtf(var + 1e-5f);
    }

    #pragma unroll
    for (int nt = 0; nt < 8; ++nt)
        #pragma unroll
        for (int reg = 0; reg < 4; ++reg) {
            int gr = node0 + mr + lg * 4 + reg;
            if (gr < n) {
                float v = c2[nt][reg] + b2v[nt];
                out[gr * 128 + nt * 16 + lr] = gv[nt] * (v - mu[reg]) * rstd[reg] + bev[nt];
            }
        }
}

extern "C" void kernel_launch(void* const* d_in, const int* in_sizes, int n_in,
                              void* d_out, int out_size, void* d_ws, size_t ws_size,
                              hipStream_t stream) {
    const float* x     = (const float*)d_in[0];
    const int*   ei    = (const int*)d_in[1];
    const float* ew    = (const float*)d_in[2];
    const float* W1    = (const float*)d_in[3];
    const float* b1    = (const float*)d_in[4];
    const float* W2    = (const float*)d_in[5];
    const float* b2    = (const float*)d_in[6];
    const float* gamma = (const float*)d_in[7];
    const float* beta  = (const float*)d_in[8];

    int n = in_sizes[0] / D;
    int E = in_sizes[2];
    const int* src = ei;
    const int* tgt = ei + E;

    char* ws = (char*)d_ws;
    int2*     stage  = (int2*)ws;     ws += (size_t)E * sizeof(int2);
    unsigned* xh     = (unsigned*)ws; ws += (size_t)n * 64 * sizeof(unsigned);
    unsigned* cmb    = (unsigned*)ws; ws += (size_t)n * 64 * sizeof(unsigned);
    unsigned short* W1t = (unsigned short*)ws; ws += 128 * 128 * sizeof(unsigned short);
    unsigned short* W2t = (unsigned short*)ws; ws += 128 * 128 * sizeof(unsigned short);
    int*      bcnt   = (int*)ws;      ws += NBMAX * sizeof(int);
    int*      bbase  = (int*)ws;      ws += (NBMAX + 1) * sizeof(int);
    int*      bcur   = (int*)ws;      ws += NBMAX * sizeof(int);

    hipMemsetAsync((void*)bcnt, 0, NBMAX * sizeof(int), stream);

    int nbuk = (n + BN - 1) >> BSH;                 // 782 for n=100000 (<= NBMAX)
    int nf4 = n * D / 4;
    k_prep<<<2048, 256, 0, stream>>>(x, xh, nf4, W1, W2, W1t, W2t, tgt, bcnt, E, nbuk);

    k_scanB<<<1, 256, 0, stream>>>(bcnt, bbase, bcur, nbuk, E);

    int nchunk = (E + CH - 1) / CH;                 // 782
    k_binA<<<nchunk, 256, 0, stream>>>(src, tgt, ew, bcur, stage, E, nbuk);

    k_fuse<<<nbuk, 256, 0, stream>>>(bbase, stage,
                                     (const uint4v*)xh, (uint4v*)cmb, n);

    k_mlp<<<(n + 63) / 64, 256, 0, stream>>>((const uint4v*)cmb, W1t, W2t,
                                             b1, b2, gamma, beta,
                                             (float*)d_out, n);
}

// Round 13
// 253.988 us; speedup vs baseline: 18.9190x; 18.9190x over previous
//
#include <hip/hip_runtime.h>
#include <hip/hip_bf16.h>

#define D 128
#define CH 2048          // edges per k_binA block
#define BSH 9            // log2(nodes per bucket) -> 512; valid for n <= 131072
#define CNT_BLK 512      // blocks doing bucket counting in k_prep

typedef __attribute__((ext_vector_type(8))) short short8;
typedef __attribute__((ext_vector_type(4))) float f32x4;
typedef __attribute__((ext_vector_type(4))) int int4v;
typedef __attribute__((ext_vector_type(2))) int int2v;
typedef __attribute__((ext_vector_type(4))) float float4v;
typedef __attribute__((ext_vector_type(4))) unsigned uint4v;
typedef __attribute__((ext_vector_type(2))) unsigned uint2v;
typedef _Float16 half2_t __attribute__((ext_vector_type(2)));

__device__ __forceinline__ unsigned short us_bf16(float f) {
    return __bfloat16_as_ushort(__float2bfloat16(f));
}
__device__ __forceinline__ unsigned pack_bf16(float a, float b) {
    return (unsigned)us_bf16(a) | ((unsigned)us_bf16(b) << 16);
}
__device__ __forceinline__ unsigned pack_f16(float a, float b) {
    unsigned short ua = __builtin_bit_cast(unsigned short, (_Float16)a);
    unsigned short ub = __builtin_bit_cast(unsigned short, (_Float16)b);
    return (unsigned)ua | ((unsigned)ub << 16);
}
__device__ __forceinline__ half2_t as_h2(unsigned u) {
    return __builtin_bit_cast(half2_t, u);
}
__device__ __forceinline__ half2_t shfl_h2(half2_t v, int mask) {
    return __builtin_bit_cast(half2_t,
        (unsigned)__shfl_xor(__builtin_bit_cast(int, v), mask));
}
__device__ __forceinline__ int2v nt_load2(const int2* p) {
    return __builtin_nontemporal_load(reinterpret_cast<const int2v*>(p));
}

// ---------- prep: x->f16, W->bf16 transposed, per-BUCKET count (196 bins in LDS) ----------
__global__ __launch_bounds__(256) void k_prep(const float* __restrict__ x,
                                              unsigned* __restrict__ xh, int nf4,
                                              const float* __restrict__ W1,
                                              const float* __restrict__ W2,
                                              unsigned short* __restrict__ W1t,
                                              unsigned short* __restrict__ W2t,
                                              const int* __restrict__ tgt,
                                              int* __restrict__ bcnt, int E, int nbuk) {
    int tid = threadIdx.x;
    int i0 = blockIdx.x * blockDim.x + tid;
    int stride = gridDim.x * blockDim.x;
    const float4v* x4 = reinterpret_cast<const float4v*>(x);
    uint2v* xh2 = reinterpret_cast<uint2v*>(xh);
    for (int i = i0; i < nf4; i += stride) {
        float4v v = x4[i];
        uint2v o;
        o.x = pack_f16(v.x, v.y);
        o.y = pack_f16(v.z, v.w);
        xh2[i] = o;
    }
    if (i0 < 16384) {
        int k = i0 >> 7, nn = i0 & 127;
        W1t[nn * 128 + k] = us_bf16(W1[i0]);
        W2t[nn * 128 + k] = us_bf16(W2[i0]);
    }
    // bucket counting on a subset of blocks
    __shared__ int hist[256];
    if (blockIdx.x < CNT_BLK) {
        hist[tid] = 0;
        __syncthreads();
        int c0 = blockIdx.x * 256 + tid;
        int cstride = CNT_BLK * 256;
        int E4 = E >> 2;
        const int4v* tgt4 = reinterpret_cast<const int4v*>(tgt);
        for (int q = c0; q < E4; q += cstride) {
            int4v t4 = __builtin_nontemporal_load(&tgt4[q]);
            atomicAdd(&hist[t4.x >> BSH], 1);
            atomicAdd(&hist[t4.y >> BSH], 1);
            atomicAdd(&hist[t4.z >> BSH], 1);
            atomicAdd(&hist[t4.w >> BSH], 1);
        }
        for (int e = E4 * 4 + c0; e < E; e += cstride)
            atomicAdd(&hist[tgt[e] >> BSH], 1);
        __syncthreads();
        if (tid < nbuk && hist[tid] > 0) atomicAdd(&bcnt[tid], hist[tid]);
    }
}

// ---------- tiny: scan bucket counts -> bbase/bcur; set rowptr[n]=E ----------
__global__ __launch_bounds__(256) void k_scanB(const int* __restrict__ bcnt,
                                               int* __restrict__ bbase,
                                               int* __restrict__ bcur,
                                               int* __restrict__ rowptr,
                                               int nbuk, int n, int E) {
    __shared__ int sp[256];
    int t = threadIdx.x;
    int v = (t < nbuk) ? bcnt[t] : 0;
    sp[t] = v; __syncthreads();
    for (int off = 1; off < 256; off <<= 1) {
        int o = (t >= off) ? sp[t - off] : 0;
        __syncthreads();
        sp[t] += o;
        __syncthreads();
    }
    int excl = sp[t] - v;
    if (t < nbuk) { bbase[t] = excl; bcur[t] = excl; }
    if (t == 0) { bbase[nbuk] = E; rowptr[n] = E; }
}

// ---------- pass A: LDS-binned bucket append ----------
__global__ __launch_bounds__(256) void k_binA(
    const int* __restrict__ src, const int* __restrict__ tgt,
    const float* __restrict__ ew, int* __restrict__ bcur,
    int2* __restrict__ stage, int E, int nbuk)
{
    __shared__ int2 recs[CH];
    __shared__ unsigned short bslot[CH];
    __shared__ int sh[256];
    __shared__ int lbase[256];
    __shared__ int gofs[256];

    int tid = threadIdx.x;
    int c0 = blockIdx.x * CH;
    int chunkCnt = min(CH, E - c0);

    sh[tid] = 0;
    __syncthreads();

    int myb[8], mypos[8], mysrc[8]; unsigned myy[8];
    #pragma unroll
    for (int k = 0; k < 8; ++k) {
        int idx = k * 256 + tid;
        myb[k] = -1;
        if (idx < chunkCnt) {
            int e = c0 + idx;
            int t = __builtin_nontemporal_load(&tgt[e]);
            int b = t >> BSH;
            float expw = __expf(__builtin_nontemporal_load(&ew[e]));
            unsigned short h = __builtin_bit_cast(unsigned short, (_Float16)expw);
            myb[k] = b;
            myy[k] = ((unsigned)(t & ((1 << BSH) - 1)) << 16) | (unsigned)h;
            mysrc[k] = __builtin_nontemporal_load(&src[e]);
            mypos[k] = atomicAdd(&sh[b], 1);
        }
    }
    __syncthreads();
    int cnt_b = sh[tid];
    for (int off = 1; off < 256; off <<= 1) {
        int o = (tid >= off) ? sh[tid - off] : 0;
        __syncthreads();
        sh[tid] += o;
        __syncthreads();
    }
    int lb = sh[tid] - cnt_b;
    lbase[tid] = lb;
    if (cnt_b > 0 && tid < nbuk) {
        int gb = atomicAdd(&bcur[tid], cnt_b);
        gofs[tid] = gb - lb;
    }
    __syncthreads();
    #pragma unroll
    for (int k = 0; k < 8; ++k) {
        if (myb[k] >= 0) {
            int slot = lbase[myb[k]] + mypos[k];
            recs[slot] = make_int2(mysrc[k], (int)myy[k]);
            bslot[slot] = (unsigned short)myb[k];
        }
    }
    __syncthreads();
    for (int i = tid; i < chunkCnt; i += 256) {
        int b = bslot[i];
        stage[gofs[b] + i] = recs[i];
    }
}

// ---------- pass B: per-bucket CSR build (count+scan+rowptr in LDS) + normalize ----------
__global__ __launch_bounds__(256) void k_binB(
    const int* __restrict__ bbase, const int2* __restrict__ stage,
    int2* __restrict__ csr, int* __restrict__ rowptr, int n)
{
    __shared__ int lcnt[1 << BSH];     // counts, then cursors
    __shared__ float ldenom[1 << BSH];
    __shared__ int sc[256];
    int b = blockIdx.x;
    int tid = threadIdx.x;
    int node0 = b << BSH;
    int nn = min(1 << BSH, n - node0);
    int s0 = bbase[b], s1 = bbase[b + 1];

    for (int j = tid; j < (1 << BSH); j += 256) { lcnt[j] = 0; ldenom[j] = 0.f; }
    __syncthreads();

    // pass 1: per-node count + softmax denominator
    for (int i = s0 + tid; i < s1; i += 256) {
        int2v rec = nt_load2(&stage[i]);
        int tl = ((unsigned)rec.y) >> 16;
        _Float16 hw = __builtin_bit_cast(_Float16, (unsigned short)(rec.y & 0xffff));
        atomicAdd(&lcnt[tl], 1);
        atomicAdd(&ldenom[tl], (float)hw);
    }
    __syncthreads();

    // invert denominators
    for (int j = tid; j < (1 << BSH); j += 256) {
        float d = ldenom[j];
        ldenom[j] = (d > 0.f) ? (1.f / d) : 0.f;
    }
    // scan 512 counts with 256 threads (2 per thread) -> rowptr + cursors
    int v0 = lcnt[2 * tid], v1 = lcnt[2 * tid + 1];
    int tsum = v0 + v1;
    sc[tid] = tsum;
    __syncthreads();
    for (int off = 1; off < 256; off <<= 1) {
        int o = (tid >= off) ? sc[tid - off] : 0;
        __syncthreads();
        sc[tid] += o;
        __syncthreads();
    }
    int excl = sc[tid] - tsum;
    int p0 = s0 + excl, p1 = s0 + excl + v0;
    if (2 * tid < nn)     rowptr[node0 + 2 * tid] = p0;
    if (2 * tid + 1 < nn) rowptr[node0 + 2 * tid + 1] = p1;
    __syncthreads();
    lcnt[2 * tid] = p0;
    lcnt[2 * tid + 1] = p1;
    __syncthreads();

    // pass 2: scatter normalized records into block-private csr window
    for (int i = s0 + tid; i < s1; i += 256) {
        int2v rec = nt_load2(&stage[i]);
        int tl = ((unsigned)rec.y) >> 16;
        _Float16 hw = __builtin_bit_cast(_Float16, (unsigned short)(rec.y & 0xffff));
        float wn = (float)hw * ldenom[tl];
        unsigned short wb = __builtin_bit_cast(unsigned short, (_Float16)wn);
        unsigned wp = (unsigned)wb | ((unsigned)wb << 16);
        int pos = atomicAdd(&lcnt[tl], 1);
        csr[pos] = make_int2(rec.x, (int)wp);
    }
}

// ---------- aggregate: 1 wave per node; 8 edges in flight per wave ----------
__global__ __launch_bounds__(256) void k_agg(
    const int* __restrict__ rowptr, const int2* __restrict__ csr,
    const uint4v* __restrict__ xh4, uint4v* __restrict__ cmb4, int n)
{
    int w = threadIdx.x >> 6;
    int lane = threadIdx.x & 63;
    int node = blockIdx.x * 4 + w;
    if (node >= n) node = n - 1;   // benign duplicate on tail

    int r0 = rowptr[node], r1 = rowptr[node + 1];
    int cnt = r1 - r0;

    int eg = lane >> 4;
    int dg = lane & 15;

    half2_t h0 = (half2_t)0, h1 = (half2_t)0, h2 = (half2_t)0, h3 = (half2_t)0;

    int last = (cnt > 0) ? cnt - 1 : 0;
    for (int base = 0; base < cnt; base += 32) {
        #pragma unroll
        for (int i = 0; i < 8; ++i) {
            if (base + i * 4 >= cnt) break;    // wave-uniform
            int e = base + i * 4 + eg;
            bool valid = e < cnt;
            int2v cr = nt_load2(&csr[r0 + (valid ? e : last)]);
            half2_t w2 = as_h2(valid ? (unsigned)cr.y : 0u);
            uint4v v = xh4[cr.x * 16 + dg];
            h0 += w2 * as_h2(v.x);
            h1 += w2 * as_h2(v.y);
            h2 += w2 * as_h2(v.z);
            h3 += w2 * as_h2(v.w);
        }
    }

    h0 += shfl_h2(h0, 16); h0 += shfl_h2(h0, 32);
    h1 += shfl_h2(h1, 16); h1 += shfl_h2(h1, 32);
    h2 += shfl_h2(h2, 16); h2 += shfl_h2(h2, 32);
    h3 += shfl_h2(h3, 16); h3 += shfl_h2(h3, 32);

    float a0 = (float)h0.x, a1 = (float)h0.y, a2 = (float)h1.x, a3 = (float)h1.y;
    float a4 = (float)h2.x, a5 = (float)h2.y, a6 = (float)h3.x, a7 = (float)h3.y;

    float ss = a0 * a0;
    ss = fmaf(a1, a1, ss); ss = fmaf(a2, a2, ss); ss = fmaf(a3, a3, ss);
    ss = fmaf(a4, a4, ss); ss = fmaf(a5, a5, ss); ss = fmaf(a6, a6, ss);
    ss = fmaf(a7, a7, ss);
    #pragma unroll
    for (int off = 8; off; off >>= 1) ss += __shfl_xor(ss, off);
    float rn = 1.f / (sqrtf(ss) + 1e-9f);

    if (eg == 0) {
        uint4v hx = xh4[node * 16 + dg];
        half2_t x0 = as_h2(hx.x), x1 = as_h2(hx.y), x2 = as_h2(hx.z), x3 = as_h2(hx.w);
        uint4v o;
        o.x = pack_bf16((float)x0.x + a0 * rn, (float)x0.y + a1 * rn);
        o.y = pack_bf16((float)x1.x + a2 * rn, (float)x1.y + a3 * rn);
        o.z = pack_bf16((float)x2.x + a4 * rn, (float)x2.y + a5 * rn);
        o.w = pack_bf16((float)x3.x + a6 * rn, (float)x3.y + a7 * rn);
        cmb4[node * 16 + dg] = o;
    }
}

// ---------- MLP + LN via MFMA: 64 nodes/block; W read from global (L1/L2) ----------
__global__ __launch_bounds__(256) void k_mlp(
    const uint4v* __restrict__ cmb4,
    const unsigned short* __restrict__ W1t, const unsigned short* __restrict__ W2t,
    const float* __restrict__ b1, const float* __restrict__ b2,
    const float* __restrict__ gamma, const float* __restrict__ beta,
    float* __restrict__ out, int n)
{
    __shared__ __align__(16) unsigned short sA[64][136];

    int node0 = blockIdx.x * 64;
    int w = threadIdx.x >> 6;
    int lane = threadIdx.x & 63;
    int lr = lane & 15;
    int lg = lane >> 4;
    int mr = w * 16;

    for (int idx = threadIdx.x; idx < 64 * 16; idx += 256) {
        int row = idx >> 4, seg = idx & 15;
        int gr = node0 + row; if (gr >= n) gr = n - 1;
        uint4v v = cmb4[gr * 16 + seg];
        *reinterpret_cast<uint4v*>(&sA[row][seg * 8]) = v;
    }
    __syncthreads();

    short8 aF[4];
    #pragma unroll
    for (int kt = 0; kt < 4; ++kt)
        aF[kt] = *reinterpret_cast<const short8*>(&sA[mr + lr][kt * 32 + lg * 8]);

    #pragma unroll
    for (int nt = 0; nt < 8; ++nt) {
        f32x4 c = {0.f, 0.f, 0.f, 0.f};
        #pragma unroll
        for (int kt = 0; kt < 4; ++kt) {
            short8 bF = *reinterpret_cast<const short8*>(
                &W1t[(nt * 16 + lr) * 128 + kt * 32 + lg * 8]);
            c = __builtin_amdgcn_mfma_f32_16x16x32_bf16(aF[kt], bF, c, 0, 0, 0);
        }
        float b1v = b1[nt * 16 + lr];
        #pragma unroll
        for (int reg = 0; reg < 4; ++reg) {
            float h = fmaxf(c[reg] + b1v, 0.f);
            sA[mr + lg * 4 + reg][nt * 16 + lr] = us_bf16(h);
        }
    }
    __syncthreads();

    short8 a2F[4];
    #pragma unroll
    for (int kt = 0; kt < 4; ++kt)
        a2F[kt] = *reinterpret_cast<const short8*>(&sA[mr + lr][kt * 32 + lg * 8]);

    f32x4 c2[8];
    float b2v[8], gv[8], bev[8];
    #pragma unroll
    for (int nt = 0; nt < 8; ++nt) {
        c2[nt] = (f32x4){0.f, 0.f, 0.f, 0.f};
        #pragma unroll
        for (int kt = 0; kt < 4; ++kt) {
            short8 bF = *reinterpret_cast<const short8*>(
                &W2t[(nt * 16 + lr) * 128 + kt * 32 + lg * 8]);
            c2[nt] = __builtin_amdgcn_mfma_f32_16x16x32_bf16(a2F[kt], bF, c2[nt], 0, 0, 0);
        }
        int col = nt * 16 + lr;
        b2v[nt] = b2[col]; gv[nt] = gamma[col]; bev[nt] = beta[col];
    }

    float rs[4] = {0.f, 0.f, 0.f, 0.f}, sq[4] = {0.f, 0.f, 0.f, 0.f};
    #pragma unroll
    for (int nt = 0; nt < 8; ++nt)
        #pragma unroll
        for (int reg = 0; reg < 4; ++reg) {
            float v = c2[nt][reg] + b2v[nt];
            rs[reg] += v; sq[reg] += v * v;
        }
    #pragma unroll
    for (int off = 1; off <= 8; off <<= 1)
        #pragma unroll
        for (int reg = 0; reg < 4; ++reg) {
            rs[reg] += __shfl_xor(rs[reg], off);
            sq[reg] += __shfl_xor(sq[reg], off);
        }
    float mu[4], rstd[4];
    #pragma unroll
    for (int reg = 0; reg < 4; ++reg) {
        mu[reg] = rs[reg] * (1.f / 128.f);
        float var = sq[reg] * (1.f / 128.f) - mu[reg] * mu[reg];
        rstd[reg] = rsqrtf(var + 1e-5f);
    }

    #pragma unroll
    for (int nt = 0; nt < 8; ++nt)
        #pragma unroll
        for (int reg = 0; reg < 4; ++reg) {
            int gr = node0 + mr + lg * 4 + reg;
            if (gr < n) {
                float v = c2[nt][reg] + b2v[nt];
                out[gr * 128 + nt * 16 + lr] = gv[nt] * (v - mu[reg]) * rstd[reg] + bev[nt];
            }
        }
}

extern "C" void kernel_launch(void* const* d_in, const int* in_sizes, int n_in,
                              void* d_out, int out_size, void* d_ws, size_t ws_size,
                              hipStream_t stream) {
    const float* x     = (const float*)d_in[0];
    const int*   ei    = (const int*)d_in[1];
    const float* ew    = (const float*)d_in[2];
    const float* W1    = (const float*)d_in[3];
    const float* b1    = (const float*)d_in[4];
    const float* W2    = (const float*)d_in[5];
    const float* b2    = (const float*)d_in[6];
    const float* gamma = (const float*)d_in[7];
    const float* beta  = (const float*)d_in[8];

    int n = in_sizes[0] / D;
    int E = in_sizes[2];
    const int* src = ei;
    const int* tgt = ei + E;

    char* ws = (char*)d_ws;
    int2*     csr    = (int2*)ws;     ws += (size_t)E * sizeof(int2);
    unsigned* xh     = (unsigned*)ws; ws += (size_t)n * 64 * sizeof(unsigned);
    unsigned* cmb    = (unsigned*)ws; ws += (size_t)n * 64 * sizeof(unsigned);
    unsigned short* W1t = (unsigned short*)ws; ws += 128 * 128 * sizeof(unsigned short);
    unsigned short* W2t = (unsigned short*)ws; ws += 128 * 128 * sizeof(unsigned short);
    int*      rowptr = (int*)ws;      ws += ((size_t)n + 1) * sizeof(int);
    int*      bcnt   = (int*)ws;      ws += 256 * sizeof(int);
    int*      bbase  = (int*)ws;      ws += 257 * sizeof(int);
    int*      bcur   = (int*)ws;      ws += 256 * sizeof(int);
    // stage aliases cmb: stage is consumed by k_binB before k_agg writes cmb
    int2*     stage  = (int2*)cmb;

    hipMemsetAsync((void*)bcnt, 0, 256 * sizeof(int), stream);

    int nbuk = (n + (1 << BSH) - 1) >> BSH;         // 196 for n=100000
    int nf4 = n * D / 4;
    k_prep<<<2048, 256, 0, stream>>>(x, xh, nf4, W1, W2, W1t, W2t, tgt, bcnt, E, nbuk);

    k_scanB<<<1, 256, 0, stream>>>(bcnt, bbase, bcur, rowptr, nbuk, n, E);

    int nchunk = (E + CH - 1) / CH;                 // 782
    k_binA<<<nchunk, 256, 0, stream>>>(src, tgt, ew, bcur, stage, E, nbuk);
    k_binB<<<nbuk, 256, 0, stream>>>(bbase, stage, csr, rowptr, n);

    k_agg<<<(n + 3) / 4, 256, 0, stream>>>(rowptr, csr,
                                           (const uint4v*)xh, (uint4v*)cmb, n);

    k_mlp<<<(n + 63) / 64, 256, 0, stream>>>((const uint4v*)cmb, W1t, W2t,
                                             b1, b2, gamma, beta,
                                             (float*)d_out, n);
}